// Round 1
// baseline (314.394 us; speedup 1.0000x reference)
//
#include <hip/hip_runtime.h>

#define NTOK 49
#define CDIM 128
#define NH 4
#define NWIN 64

typedef unsigned short u16;
typedef unsigned int u32;
typedef __bf16 bf16x8 __attribute__((ext_vector_type(8)));
typedef float f32x4 __attribute__((ext_vector_type(4)));
typedef u16 u16x4 __attribute__((ext_vector_type(4)));

// RNE f32->bf16 via compiler cast: lowers to v_cvt_pk_bf16_f32 (1 VALU op)
// instead of the 5-op integer round sequence.
__device__ __forceinline__ u16 f2bf(float f) {
  union { __bf16 h; u16 u; } c;
  c.h = (__bf16)f;
  return c.u;
}
__device__ __forceinline__ u32 pack2(float a, float b) {
  return (u32)f2bf(a) | ((u32)f2bf(b) << 16);
}
__device__ __forceinline__ bf16x8 ld8(const u16* p) { return *(const bf16x8*)p; }

// DPP add across the 16-lane row: xor1, xor2 (quad_perm), then ror4 + ror8.
#define DPP_ADD(v, ctrl)                                                            \
  v += __int_as_float(__builtin_amdgcn_update_dpp(0, __float_as_int(v), ctrl, 0xf, 0xf, true))

// ---------------- prep: transpose weights to bf16, build TRANSPOSED combined bias+mask ----
// ws layout (bytes): [0,98304) wqkvT bf16 (384x128)  [98304,131072) wprojT bf16 (128x128)
//                    [131072,131072+4MB) cmbT f32 [win][h][m(key) 64][n(query) 64], -1e30 pads
__global__ void prep_kernel(const float* __restrict__ qkv_w,
                            const float* __restrict__ proj_w,
                            const float* __restrict__ bias_table,
                            const float* __restrict__ mask,
                            const int* __restrict__ rel_index,
                            u16* __restrict__ wqkvT,
                            u16* __restrict__ wprojT,
                            float* __restrict__ cmbT) {
  int i = blockIdx.x * 256 + threadIdx.x;   // 1,048,576 threads
  if (i < 384 * 128) {
    int n = i >> 7, k = i & 127;
    wqkvT[i] = f2bf(qkv_w[k * 384 + n]);
  }
  if (i < 128 * 128) {
    int n = i >> 7, k = i & 127;
    wprojT[i] = f2bf(proj_w[k * 128 + n]);
  }
  int n = i & 63, m = (i >> 6) & 63, hh = (i >> 12) & 3, win = i >> 14;
  float v = -1e30f;
  if (n < NTOK && m < NTOK)
    v = bias_table[rel_index[n * NTOK + m] * NH + hh] + mask[(win * NTOK + n) * NTOK + m];
  cmbT[i] = v;   // cmbT[win][h][m][n], coalesced in n
}

// ---------------- fused window attention ----------------
// LDS map (u16 units, 18432 total = 36 KB -> 4 blocks/CU):
//   R(h) = h*4608 (wave-private region of head h):
//     Q : R(h)        + row*36 + d     (64x36, d=0..31)
//     K : R(h) + 2304 + row*36 + d
//     P : R(h)        + row*68 + m     (64x68) -- overlays Q/K after they are read
//     AO: R(h) + 2304 + row*36 + d     -- overlays P tail after PV done
// x is NOT staged in LDS: each wave loads its A-fragments straight from global
// (32 B contiguous per lane; x block is L2/L3 resident) and converts f32->bf16
// in registers. This removes phase A, one barrier, and 16 KB of LDS.
#define RGN(h) ((h) * 4608)

__global__ __launch_bounds__(256, 4)
void swin_fused(const float* __restrict__ x, const float* __restrict__ qkv_b,
                const float* __restrict__ proj_b, const u16* __restrict__ wqkvT,
                const u16* __restrict__ wprojT, const float* __restrict__ cmbT,
                float* __restrict__ out) {
  __shared__ u16 lds[18432];
  const int tid  = threadIdx.x;
  const int w    = tid >> 6;       // wave = head
  const int lane = tid & 63;
  const int ln   = lane & 15;
  const int quad = lane >> 4;
  const int b    = blockIdx.x;
  const int win  = b & (NWIN - 1);
  const float scale = 0.17677669529663687f;  // 32^-0.5

  // ---- Phase B: wave w computes q/k/v of head w. Q,K -> private LDS; V -> registers ----
  u32 vbx[4][2], vby[4][2];   // packed bf16: V tokens (4q+0,4q+1) / (4q+2,4q+3), [tok-tile][dim-tile]
  {
    // A-fragments of x, loaded direct from global: row tm*16+ln, cols ks*32+quad*8..+7
    bf16x8 af[4][4];
    const float* xb = x + (size_t)b * (NTOK * CDIM);
#pragma unroll
    for (int tm = 0; tm < 4; ++tm) {
      int row = tm * 16 + ln;
      const float4* rp = (const float4*)(xb + row * CDIM) + (quad << 1);
      bool ok = (tm < 3) | (row < NTOK);   // rows 49..63 -> zero fragments
#pragma unroll
      for (int ks = 0; ks < 4; ++ks) {
        float4 f0 = {0.f, 0.f, 0.f, 0.f}, f1 = {0.f, 0.f, 0.f, 0.f};
        if (ok) { f0 = rp[ks * 8]; f1 = rp[ks * 8 + 1]; }
        bf16x8 v;
        v[0] = (__bf16)f0.x; v[1] = (__bf16)f0.y; v[2] = (__bf16)f0.z; v[3] = (__bf16)f0.w;
        v[4] = (__bf16)f1.x; v[5] = (__bf16)f1.y; v[6] = (__bf16)f1.z; v[7] = (__bf16)f1.w;
        af[tm][ks] = v;
      }
    }

#pragma unroll
    for (int tl = 0; tl < 6; ++tl) {
      int sect = tl >> 1, tc = tl & 1;
      int colg = sect * 128 + w * 32 + tc * 16 + ln;
      bf16x8 bw[4];
#pragma unroll
      for (int ks = 0; ks < 4; ++ks)
        bw[ks] = ld8(wqkvT + colg * 128 + ks * 32 + quad * 8);
      float cb = qkv_b[colg];
#pragma unroll
      for (int tm = 0; tm < 4; ++tm) {
        f32x4 acc = {0.f, 0.f, 0.f, 0.f};
#pragma unroll
        for (int ks = 0; ks < 4; ++ks)
          acc = __builtin_amdgcn_mfma_f32_16x16x32_bf16(af[tm][ks], bw[ks], acc, 0, 0, 0);
        int row0 = tm * 16 + quad * 4;   // C-layout: col=ln, row=quad*4+r
        if (sect == 0) {
#pragma unroll
          for (int r = 0; r < 4; ++r)
            lds[RGN(w) + (row0 + r) * 36 + tc * 16 + ln] = f2bf((acc[r] + cb) * scale);
        } else if (sect == 1) {
#pragma unroll
          for (int r = 0; r < 4; ++r)
            lds[RGN(w) + 2304 + (row0 + r) * 36 + tc * 16 + ln] = f2bf(acc[r] + cb);
        } else {
          vbx[tm][tc] = pack2(acc[0] + cb, acc[1] + cb);
          vby[tm][tc] = pack2(acc[2] + cb, acc[3] + cb);
        }
      }
    }
  }
  // no barrier: everything below (until phase E) reads only wave-private regions

  // ---- Phase C: S = Q K^T, + bias+mask (cmbT float4), exp (no max-sub: |s| small
  //      enough that fp32 exp never overflows; masked/pad lanes underflow to 0),
  //      row-sum via DPP, P (UNNORMALIZED) -> private LDS ----
  f32x4 s[4][4];
  {
    bf16x8 aq[4];
#pragma unroll
    for (int tm = 0; tm < 4; ++tm)
      aq[tm] = ld8(&lds[RGN(w) + (tm * 16 + ln) * 36 + quad * 8]);
#pragma unroll
    for (int tn = 0; tn < 4; ++tn) {
      bf16x8 bk = ld8(&lds[RGN(w) + 2304 + (tn * 16 + ln) * 36 + quad * 8]);
#pragma unroll
      for (int tm = 0; tm < 4; ++tm) {
        f32x4 z = {0.f, 0.f, 0.f, 0.f};
        s[tm][tn] = __builtin_amdgcn_mfma_f32_16x16x32_bf16(aq[tm], bk, z, 0, 0, 0);
      }
    }
  }
  {
    const float* cb = cmbT + ((size_t)((win << 2) | w) << 12);
#pragma unroll
    for (int tm = 0; tm < 4; ++tm) {
#pragma unroll
      for (int tn = 0; tn < 4; ++tn) {
        f32x4 c4 = *(const f32x4*)&cb[(tn * 16 + ln) * 64 + tm * 16 + quad * 4];
        s[tm][tn] += c4;
      }
    }
  }
  float inv[4][4];
#pragma unroll
  for (int tm = 0; tm < 4; ++tm) {
    int row0 = tm * 16 + quad * 4;
#pragma unroll
    for (int r = 0; r < 4; ++r) {
      float e0 = __expf(s[tm][0][r]);
      float e1 = __expf(s[tm][1][r]);
      float e2 = __expf(s[tm][2][r]);
      float e3 = __expf(s[tm][3][r]);
      float t = (e0 + e1) + (e2 + e3);
      DPP_ADD(t, 0xB1);   // quad_perm [1,0,3,2] : xor 1
      DPP_ADD(t, 0x4E);   // quad_perm [2,3,0,1] : xor 2
      DPP_ADD(t, 0x124);  // row_ror:4
      DPP_ADD(t, 0x128);  // row_ror:8
      inv[tm][r] = 1.0f / t;
      int rr = row0 + r;
      lds[RGN(w) + rr * 68 + 0 * 16 + ln] = f2bf(e0);
      lds[RGN(w) + rr * 68 + 1 * 16 + ln] = f2bf(e1);
      lds[RGN(w) + rr * 68 + 2 * 16 + ln] = f2bf(e2);
      lds[RGN(w) + rr * 68 + 3 * 16 + ln] = f2bf(e3);
    }
  }

  // ---- Phase D: O = P @ V (unnormalized); V B-frags via register shuffle;
  //      scale by 1/rowsum at the store; AO -> private LDS ----
  {
    f32x4 o[4][2];
#pragma unroll
    for (int tm = 0; tm < 4; ++tm)
#pragma unroll
      for (int tc = 0; tc < 2; ++tc) { f32x4 z = {0.f,0.f,0.f,0.f}; o[tm][tc] = z; }
#pragma unroll
    for (int ks = 0; ks < 2; ++ks) {
      bf16x8 pa[4];
#pragma unroll
      for (int tm = 0; tm < 4; ++tm)
        pa[tm] = ld8(&lds[RGN(w) + (tm * 16 + ln) * 68 + ks * 32 + quad * 8]);
#pragma unroll
      for (int tc = 0; tc < 2; ++tc) {
        union { u32 u[4]; bf16x8 v; } bv;
#pragma unroll
        for (int p = 0; p < 4; ++p) {
          int src = ((2 * (quad & 1) + (p >> 1)) << 4) | ln;
          int a0 = __shfl((int)((p & 1) ? vby[2 * ks][tc]     : vbx[2 * ks][tc]),     src);
          int a1 = __shfl((int)((p & 1) ? vby[2 * ks + 1][tc] : vbx[2 * ks + 1][tc]), src);
          bv.u[p] = (u32)((quad < 2) ? a0 : a1);
        }
#pragma unroll
        for (int tm = 0; tm < 4; ++tm)
          o[tm][tc] = __builtin_amdgcn_mfma_f32_16x16x32_bf16(pa[tm], bv.v, o[tm][tc], 0, 0, 0);
      }
    }
#pragma unroll
    for (int tm = 0; tm < 4; ++tm) {
      int row0 = tm * 16 + quad * 4;
#pragma unroll
      for (int tc = 0; tc < 2; ++tc)
#pragma unroll
        for (int r = 0; r < 4; ++r)
          lds[RGN(w) + 2304 + (row0 + r) * 36 + tc * 16 + ln] = f2bf(o[tm][tc][r] * inv[tm][r]);
    }
  }
  __syncthreads();

  // ---- Phase E: out = AO @ proj_w + proj_b ----
  {
    bf16x8 aof[4][4];
#pragma unroll
    for (int tm = 0; tm < 4; ++tm)
#pragma unroll
      for (int ks = 0; ks < 4; ++ks)
        aof[tm][ks] = ld8(&lds[RGN(ks) + 2304 + (tm * 16 + ln) * 36 + quad * 8]);
#pragma unroll
    for (int tj = 0; tj < 2; ++tj) {
      int colg = w * 32 + tj * 16 + ln;
      bf16x8 bw[4];
#pragma unroll
      for (int ks = 0; ks < 4; ++ks)
        bw[ks] = ld8(wprojT + colg * 128 + ks * 32 + quad * 8);
      float pb = proj_b[colg];
#pragma unroll
      for (int tm = 0; tm < 4; ++tm) {
        f32x4 acc = {0.f, 0.f, 0.f, 0.f};
#pragma unroll
        for (int ks = 0; ks < 4; ++ks)
          acc = __builtin_amdgcn_mfma_f32_16x16x32_bf16(aof[tm][ks], bw[ks], acc, 0, 0, 0);
        int row0 = tm * 16 + quad * 4;
#pragma unroll
        for (int r = 0; r < 4; ++r) {
          int rr = row0 + r;
          if (rr < NTOK)
            out[((size_t)b * NTOK + rr) * CDIM + colg] = acc[r] + pb;
        }
      }
    }
  }
}

extern "C" void kernel_launch(void* const* d_in, const int* in_sizes, int n_in,
                              void* d_out, int out_size, void* d_ws, size_t ws_size,
                              hipStream_t stream) {
  const float* x          = (const float*)d_in[0];
  const float* qkv_w      = (const float*)d_in[1];
  const float* qkv_b      = (const float*)d_in[2];
  const float* proj_w     = (const float*)d_in[3];
  const float* proj_b     = (const float*)d_in[4];
  const float* bias_table = (const float*)d_in[5];
  const float* mask       = (const float*)d_in[6];
  const int*   rel_index  = (const int*)d_in[7];

  u16*   wqkvT  = (u16*)d_ws;
  u16*   wprojT = wqkvT + 384 * 128;
  float* cmbT   = (float*)((char*)d_ws + 131072);

  const int Bt = in_sizes[0] / (NTOK * CDIM);   // 4096

  prep_kernel<<<4096, 256, 0, stream>>>(qkv_w, proj_w, bias_table, mask, rel_index,
                                        wqkvT, wprojT, cmbT);
  swin_fused<<<Bt, 256, 0, stream>>>(x, qkv_b, proj_b, wqkvT, wprojT, cmbT, (float*)d_out);
}